// Round 3
// baseline (1505.560 us; speedup 1.0000x reference)
//
#include <hip/hip_runtime.h>
#include <stdint.h>

#define IGNORE_INDEX (-100)

typedef __attribute__((ext_vector_type(8))) short bf16x8;
typedef __attribute__((ext_vector_type(4))) float f32x4;

static constexpr int Bv = 4, Sv = 2048, Dv = 2048, Vv = 32000;
static constexpr int Nv = Bv * (Sv - 1);   // 8188 valid rows
static constexpr int NP = 8192;            // padded row count
static constexpr int BM = 256;             // block tile (rows and cols)
static constexpr int BK = 64;              // K-step
static constexpr int NT = Dv / BK;         // 32 K-tiles (16 iterations x 2)

typedef const __attribute__((address_space(1))) unsigned int* gptr_t;
typedef __attribute__((address_space(3))) unsigned int* lptr_t;

__device__ __forceinline__ unsigned short f2bf(float f) {
    unsigned int u = __float_as_uint(f);
    u += 0x7fffu + ((u >> 16) & 1u);   // round-to-nearest-even
    return (unsigned short)(u >> 16);
}

// ---- fp32 -> bf16 for lm_head_weight [V, D] -------------------------------
__global__ void convert_w_kernel(const float* __restrict__ w,
                                 unsigned short* __restrict__ wbf) {
    int i = blockIdx.x * blockDim.x + threadIdx.x;   // one float4
    const float4 v = ((const float4*)w)[i];
    ushort4 o;
    o.x = f2bf(v.x); o.y = f2bf(v.y); o.z = f2bf(v.z); o.w = f2bf(v.w);
    ((ushort4*)wbf)[i] = o;
}

// ---- fp32 -> bf16 for shifted hidden states, rows padded to 8192 ----------
__global__ void convert_h_kernel(const float* __restrict__ h,
                                 unsigned short* __restrict__ hbf) {
    int i = blockIdx.x * blockDim.x + threadIdx.x;   // one float4
    int e0 = i * 4;
    int n = e0 >> 11;       // / 2048
    int d = e0 & 2047;
    ushort4 o;
    if (n < Nv) {
        int b = n / 2047;            // batch
        int s = n - b * 2047;        // position 0..2046
        const float4 v = *(const float4*)(h + ((size_t)b * Sv + s) * Dv + d);
        o.x = f2bf(v.x); o.y = f2bf(v.y); o.z = f2bf(v.z); o.w = f2bf(v.w);
    } else {
        o.x = 0; o.y = 0; o.z = 0; o.w = 0;
    }
    ((ushort4*)hbf)[i] = o;
}

// ---- shifted labels + zero-init of accumulators ---------------------------
__global__ void prep_meta_kernel(const int* __restrict__ labels,
                                 int* __restrict__ t,
                                 float* __restrict__ sumexp,
                                 float* __restrict__ gold) {
    int n = blockIdx.x * blockDim.x + threadIdx.x;
    if (n >= NP) return;
    sumexp[n] = 0.0f;
    gold[n] = 0.0f;
    int tv = IGNORE_INDEX;
    if (n < Nv) {
        int b = n / 2047;
        int s = n - b * 2047;
        tv = labels[b * Sv + s + 1];   // causal shift
    }
    t[n] = tv;
}

// ---- fused GEMM + exp-reduce + gold gather --------------------------------
// 8-phase schedule with ONE-PHASE REGISTER PREFETCH: phase p issues the
// ds_reads for phase p+1's fragments, then waits only lgkmcnt(K_issued) so
// the PREVIOUS phase's reads are complete -> current reads drain under the
// MFMA cluster (LDS port || MFMA pipe overlap). Double frag sets aE/aO,
// bE/bO (all statically indexed). Stage map shifted +1 phase vs the
// drain-per-phase variant (WAR needs a 2-phase gap now):
//   ph1: A1.h1<-2j+1; ph2/3: B0<-2j+2; ph4/5: A0<-2j+2;
//   ph6/7: B1<-2j+3; ph8: A1.h0<-2j+3.
// Counted waits (ledger verified): vm8@ph1, vm4@ph3, vm6@ph7; >=4 loads
// always in flight. Peel: vm0@ph3, no reads at ph8.
// LDS XOR-swizzle (chunk ^= row&7) on the PRODUCER side (global src perm).
__global__ __launch_bounds__(512, 2)
void ce_gemm(const unsigned short* __restrict__ hbf,
             const unsigned short* __restrict__ wbf,
             const int* __restrict__ t,
             float* __restrict__ sumexp,
             float* __restrict__ gold) {
    __shared__ unsigned short lds_a[2][BM * BK];   // 2 x 32 KiB
    __shared__ unsigned short lds_b[2][BM * BK];   // 2 x 32 KiB
    __shared__ float lds_rowsum[BM];
    __shared__ int lds_t[BM];

    const int tid  = threadIdx.x;
    const int lane = tid & 63;
    const int wave = tid >> 6;      // 0..7
    const int wr   = wave >> 2;     // 0..1
    const int wc   = wave & 3;      // 0..3
    const int quad = lane >> 4;
    const int l15  = lane & 15;

    // bijective XCD swizzle (nwg = 4000, divisible by 8): groups the 32
    // blocks sharing one B-panel onto one XCD's L2.
    const int GX  = NP / BM;                       // 32
    const int nwg = GX * (Vv / BM);                // 4000
    int fid = blockIdx.y * GX + blockIdx.x;
    fid = (fid & 7) * (nwg >> 3) + (fid >> 3);
    const int R0 = (fid & (GX - 1)) * BM;
    const int C0 = (fid / GX) * BM;

    f32x4 acc[8][4];
    const f32x4 z = {0.f, 0.f, 0.f, 0.f};
#pragma unroll
    for (int mi = 0; mi < 8; ++mi)
#pragma unroll
        for (int ni = 0; ni < 4; ++ni)
            acc[mi][ni] = z;

    // staging: thread tid owns LDS chunk (row = tid>>3, jl = tid&7);
    // fetches global chunk jg = jl ^ (row & 7) -> swizzled LDS layout.
    const int ld_r = tid >> 3;                       // 0..63
    const int jg   = (tid & 7) ^ (ld_r & 7);
    const unsigned short* ga = hbf + (size_t)(R0 + ld_r) * Dv + jg * 8;
    const unsigned short* gb = wbf + (size_t)(C0 + ld_r) * Dv + jg * 8;

#define STAGE_HALF(DSTARR, GBASE, KT, H)                                    \
    do {                                                                    \
        _Pragma("unroll")                                                   \
        for (int _i = 2 * (H); _i < 2 * (H) + 2; ++_i) {                    \
            __builtin_amdgcn_global_load_lds(                               \
                (gptr_t)((GBASE) + (size_t)_i * 64 * Dv + (KT) * BK),       \
                (lptr_t)(&DSTARR[tid * 8 + _i * 4096]), 16, 0, 0);          \
        }                                                                   \
    } while (0)

#define LDSF(BASE, R, C) \
    (*(const bf16x8*)((BASE) + (R) * BK + (((C) ^ ((R) & 7)) * 8)))

#define VM8 asm volatile("s_waitcnt vmcnt(8)" ::: "memory")
#define VM6 asm volatile("s_waitcnt vmcnt(6)" ::: "memory")
#define VM4 asm volatile("s_waitcnt vmcnt(4)" ::: "memory")
#define VM0 asm volatile("s_waitcnt vmcnt(0)" ::: "memory")
#define NOVM ((void)0)
#define NOSTG ((void)0)

// Phase: MFMA quadrant QM from frag sets AU/BU (prefetched last phase);
// prefetch quadrant QR of lds_a[ARB] into AL (and, if LB, all-B of
// lds_b[BRB] into BL); stage STG; wait lgkmcnt(LGKM)=reads-just-issued so
// only the PREVIOUS phase's reads are forced complete.
#define PHASE(QM, AU, QR, ARB, AL, BU, LB, BRB, BL, LGKM, VMW, STG)         \
    do {                                                                    \
        STG;                                                                \
        if ((QR) >= 0) {                                                    \
            const unsigned short* ab_ = &lds_a[ARB][0];                     \
            const int r0_ = (QR) * 64 + wr * 16 + l15;                      \
            AL[0] = LDSF(ab_, r0_, quad);                                   \
            AL[1] = LDSF(ab_, r0_, quad + 4);                               \
            AL[2] = LDSF(ab_, r0_ + 32, quad);                              \
            AL[3] = LDSF(ab_, r0_ + 32, quad + 4);                          \
        }                                                                   \
        if (LB) {                                                           \
            const unsigned short* bb_ = &lds_b[BRB][0];                     \
            _Pragma("unroll")                                               \
            for (int ni_ = 0; ni_ < 4; ++ni_) {                             \
                const int br_ = wc * 64 + ni_ * 16 + l15;                   \
                BL[ni_][0] = LDSF(bb_, br_, quad);                          \
                BL[ni_][1] = LDSF(bb_, br_, quad + 4);                      \
            }                                                               \
        }                                                                   \
        __builtin_amdgcn_s_barrier();                                       \
        asm volatile("s_waitcnt lgkmcnt(" LGKM ")" ::: "memory");           \
        __builtin_amdgcn_sched_barrier(0);                                  \
        __builtin_amdgcn_s_setprio(1);                                      \
        _Pragma("unroll")                                                   \
        for (int ni_ = 0; ni_ < 4; ++ni_) {                                 \
            acc[2*(QM)][ni_] = __builtin_amdgcn_mfma_f32_16x16x32_bf16(     \
                AU[0], BU[ni_][0], acc[2*(QM)][ni_], 0, 0, 0);              \
            acc[2*(QM)][ni_] = __builtin_amdgcn_mfma_f32_16x16x32_bf16(     \
                AU[1], BU[ni_][1], acc[2*(QM)][ni_], 0, 0, 0);              \
        }                                                                   \
        _Pragma("unroll")                                                   \
        for (int ni_ = 0; ni_ < 4; ++ni_) {                                 \
            acc[2*(QM)+1][ni_] = __builtin_amdgcn_mfma_f32_16x16x32_bf16(   \
                AU[2], BU[ni_][0], acc[2*(QM)+1][ni_], 0, 0, 0);            \
            acc[2*(QM)+1][ni_] = __builtin_amdgcn_mfma_f32_16x16x32_bf16(   \
                AU[3], BU[ni_][1], acc[2*(QM)+1][ni_], 0, 0, 0);            \
        }                                                                   \
        __builtin_amdgcn_s_setprio(0);                                      \
        VMW;                                                                \
        __builtin_amdgcn_s_barrier();                                       \
    } while (0)

    bf16x8 aE[4], aO[4];
    bf16x8 bE[4][2], bO[4][2];

    // ---- prologue: stage t0 fully + t1 (B + A.h0); land t0; prefetch ----
    STAGE_HALF(lds_b[0], gb, 0, 0);
    STAGE_HALF(lds_b[0], gb, 0, 1);
    STAGE_HALF(lds_a[0], ga, 0, 0);
    STAGE_HALF(lds_a[0], ga, 0, 1);
    STAGE_HALF(lds_b[1], gb, 1, 0);
    STAGE_HALF(lds_b[1], gb, 1, 1);
    STAGE_HALF(lds_a[1], ga, 1, 0);
    asm volatile("s_waitcnt vmcnt(6)" ::: "memory");   // t0's 8 loads landed
    __builtin_amdgcn_s_barrier();

    // prologue prefetch for ph1: A0.Q0 -> aE, B0 -> bE (12 reads)
    {
        const unsigned short* ab_ = &lds_a[0][0];
        const int r0_ = 0 * 64 + wr * 16 + l15;
        aE[0] = LDSF(ab_, r0_, quad);
        aE[1] = LDSF(ab_, r0_, quad + 4);
        aE[2] = LDSF(ab_, r0_ + 32, quad);
        aE[3] = LDSF(ab_, r0_ + 32, quad + 4);
        const unsigned short* bb_ = &lds_b[0][0];
#pragma unroll
        for (int ni_ = 0; ni_ < 4; ++ni_) {
            const int br_ = wc * 64 + ni_ * 16 + l15;
            bE[ni_][0] = LDSF(bb_, br_, quad);
            bE[ni_][1] = LDSF(bb_, br_, quad + 4);
        }
    }

    // ---- main loop: iterations 0..14 (tiles 0..29) ----
#pragma unroll 1
    for (int j = 0; j < 15; ++j) {
        const int t1 = 2 * j + 1, t2 = 2 * j + 2, t3 = 2 * j + 3;
        PHASE(0, aE, 1, 0, aO, bE, 0, 0, bO, "4",  VM8,  STAGE_HALF(lds_a[1], ga, t1, 1));
        PHASE(1, aO, 2, 0, aE, bE, 0, 0, bO, "4",  NOVM, STAGE_HALF(lds_b[0], gb, t2, 0));
        PHASE(2, aE, 3, 0, aO, bE, 0, 0, bO, "4",  VM4,  STAGE_HALF(lds_b[0], gb, t2, 1));
        PHASE(3, aO, 0, 1, aE, bE, 1, 1, bO, "12", NOVM, STAGE_HALF(lds_a[0], ga, t2, 0));
        PHASE(0, aE, 1, 1, aO, bO, 0, 0, bE, "4",  NOVM, STAGE_HALF(lds_a[0], ga, t2, 1));
        PHASE(1, aO, 2, 1, aE, bO, 0, 0, bE, "4",  NOVM, STAGE_HALF(lds_b[1], gb, t3, 0));
        PHASE(2, aE, 3, 1, aO, bO, 0, 0, bE, "4",  VM6,  STAGE_HALF(lds_b[1], gb, t3, 1));
        PHASE(3, aO, 0, 0, aE, bO, 1, 0, bE, "12", NOVM, STAGE_HALF(lds_a[1], ga, t3, 0));
    }
    // ---- peeled last iteration (tiles 30, 31) ----
    PHASE(0, aE, 1, 0, aO, bE, 0, 0, bO, "4",  VM8,  STAGE_HALF(lds_a[1], ga, 31, 1));
    PHASE(1, aO, 2, 0, aE, bE, 0, 0, bO, "4",  NOVM, NOSTG);
    PHASE(2, aE, 3, 0, aO, bE, 0, 0, bO, "4",  VM0,  NOSTG);
    PHASE(3, aO, 0, 1, aE, bE, 1, 1, bO, "12", NOVM, NOSTG);
    PHASE(0, aE, 1, 1, aO, bO, 0, 0, bE, "4",  NOVM, NOSTG);
    PHASE(1, aO, 2, 1, aE, bO, 0, 0, bE, "4",  NOVM, NOSTG);
    PHASE(2, aE, 3, 1, aO, bO, 0, 0, bE, "4",  NOVM, NOSTG);
    PHASE(3, aO, -1, 0, aE, bO, 0, 0, bE, "0", NOVM, NOSTG);

#undef PHASE
#undef STAGE_HALF

    // ---- fused epilogue: exp + row-sum + gold capture ----
    __syncthreads();
    if (tid < BM) {
        lds_rowsum[tid] = 0.0f;
        lds_t[tid] = t[R0 + tid];
    }
    __syncthreads();

#pragma unroll
    for (int mi = 0; mi < 8; ++mi) {
#pragma unroll
        for (int reg = 0; reg < 4; ++reg) {
            // interleaved row map: wave wr's mi-th block = mi*32 + wr*16
            const int lrow = mi * 32 + wr * 16 + quad * 4 + reg;
            const int grow = R0 + lrow;
            const int lbl  = lds_t[lrow];
            float s = 0.0f;
#pragma unroll
            for (int ni = 0; ni < 4; ++ni) {
                const float v = acc[mi][ni][reg];
                s += __expf(v);
                const int gcol = C0 + wc * 64 + ni * 16 + l15;
                if (lbl == gcol) gold[grow] = v;                // unique writer
            }
#pragma unroll
            for (int off = 1; off < 16; off <<= 1)
                s += __shfl_xor(s, off, 64);
            if (l15 == 0) atomicAdd(&lds_rowsum[lrow], s);
        }
    }
    __syncthreads();
    if (tid < BM) {
        const int grow = R0 + tid;
        if (grow < Nv) atomicAdd(&sumexp[grow], lds_rowsum[tid]);
    }
}

// ---- final scalar: mean over valid rows of log(sumexp) - gold -------------
__global__ void ce_finalize(const float* __restrict__ sumexp,
                            const float* __restrict__ gold,
                            const int* __restrict__ t,
                            float* __restrict__ out) {
    __shared__ float ssum[4];
    __shared__ float scnt[4];
    float s = 0.0f, cnt = 0.0f;
    for (int n = threadIdx.x; n < Nv; n += 256) {
        if (t[n] != IGNORE_INDEX) {
            s += logf(sumexp[n]) - gold[n];
            cnt += 1.0f;
        }
    }
#pragma unroll
    for (int off = 32; off > 0; off >>= 1) {
        s += __shfl_down(s, off, 64);
        cnt += __shfl_down(cnt, off, 64);
    }
    const int wid = threadIdx.x >> 6;
    if ((threadIdx.x & 63) == 0) { ssum[wid] = s; scnt[wid] = cnt; }
    __syncthreads();
    if (threadIdx.x == 0) {
        float S = 0.0f, C = 0.0f;
        for (int i = 0; i < 4; ++i) { S += ssum[i]; C += scnt[i]; }
        out[0] = S / fmaxf(C, 1.0f);
    }
}

extern "C" void kernel_launch(void* const* d_in, const int* in_sizes, int n_in,
                              void* d_out, int out_size, void* d_ws, size_t ws_size,
                              hipStream_t stream) {
    const float* h      = (const float*)d_in[0];   // [4, 2048, 2048] fp32
    const float* w      = (const float*)d_in[1];   // [32000, 2048] fp32
    const int*   labels = (const int*)d_in[2];     // [4, 2048] int
    float* out = (float*)d_out;

    char* ws = (char*)d_ws;
    unsigned short* hbf = (unsigned short*)ws;                                   // 33.6 MB
    unsigned short* wbf = (unsigned short*)(ws + (size_t)NP * Dv * 2);           // 131 MB
    char* tail = ws + (size_t)NP * Dv * 2 + (size_t)Vv * Dv * 2;
    float* sumexp = (float*)tail;
    float* gold   = (float*)(tail + (size_t)NP * 4);
    int*   t      = (int*)(tail + (size_t)NP * 8);

    hipLaunchKernelGGL(convert_w_kernel, dim3((Vv * Dv / 4) / 256), dim3(256), 0, stream, w, wbf);
    hipLaunchKernelGGL(convert_h_kernel, dim3((NP * Dv / 4) / 256), dim3(256), 0, stream, h, hbf);
    hipLaunchKernelGGL(prep_meta_kernel, dim3(NP / 256), dim3(256), 0, stream, labels, t, sumexp, gold);
    hipLaunchKernelGGL(ce_gemm, dim3(NP / BM, Vv / BM), dim3(512), 0, stream,
                       hbf, wbf, t, sumexp, gold);
    hipLaunchKernelGGL(ce_finalize, dim3(1), dim3(256), 0, stream, sumexp, gold, t, out);
}

// Round 4
// 1447.914 us; speedup vs baseline: 1.0398x; 1.0398x over previous
//
#include <hip/hip_runtime.h>
#include <stdint.h>

#define IGNORE_INDEX (-100)

typedef __attribute__((ext_vector_type(8))) short bf16x8;
typedef __attribute__((ext_vector_type(4))) float f32x4;

static constexpr int Bv = 4, Sv = 2048, Dv = 2048, Vv = 32000;
static constexpr int Nv = Bv * (Sv - 1);   // 8188 valid rows
static constexpr int NP = 8192;            // padded row count
static constexpr int BM = 256;             // block tile (rows and cols)
static constexpr int BK = 64;              // K-step
static constexpr int NT = Dv / BK;         // 32 K-tiles (16 iterations x 2)

typedef const __attribute__((address_space(1))) unsigned int* gptr_t;
typedef __attribute__((address_space(3))) unsigned int* lptr_t;

__device__ __forceinline__ unsigned short f2bf(float f) {
    unsigned int u = __float_as_uint(f);
    u += 0x7fffu + ((u >> 16) & 1u);   // round-to-nearest-even
    return (unsigned short)(u >> 16);
}

// ---- fp32 -> bf16 for lm_head_weight [V, D] -------------------------------
__global__ void convert_w_kernel(const float* __restrict__ w,
                                 unsigned short* __restrict__ wbf) {
    int i = blockIdx.x * blockDim.x + threadIdx.x;   // one float4
    const float4 v = ((const float4*)w)[i];
    ushort4 o;
    o.x = f2bf(v.x); o.y = f2bf(v.y); o.z = f2bf(v.z); o.w = f2bf(v.w);
    ((ushort4*)wbf)[i] = o;
}

// ---- fp32 -> bf16 for shifted hidden states, rows padded to 8192 ----------
__global__ void convert_h_kernel(const float* __restrict__ h,
                                 unsigned short* __restrict__ hbf) {
    int i = blockIdx.x * blockDim.x + threadIdx.x;   // one float4
    int e0 = i * 4;
    int n = e0 >> 11;       // / 2048
    int d = e0 & 2047;
    ushort4 o;
    if (n < Nv) {
        int b = n / 2047;            // batch
        int s = n - b * 2047;        // position 0..2046
        const float4 v = *(const float4*)(h + ((size_t)b * Sv + s) * Dv + d);
        o.x = f2bf(v.x); o.y = f2bf(v.y); o.z = f2bf(v.z); o.w = f2bf(v.w);
    } else {
        o.x = 0; o.y = 0; o.z = 0; o.w = 0;
    }
    ((ushort4*)hbf)[i] = o;
}

// ---- shifted labels + zero-init of accumulators ---------------------------
__global__ void prep_meta_kernel(const int* __restrict__ labels,
                                 int* __restrict__ t,
                                 float* __restrict__ sumexp,
                                 float* __restrict__ gold) {
    int n = blockIdx.x * blockDim.x + threadIdx.x;
    if (n >= NP) return;
    sumexp[n] = 0.0f;
    gold[n] = 0.0f;
    int tv = IGNORE_INDEX;
    if (n < Nv) {
        int b = n / 2047;
        int s = n - b * 2047;
        tv = labels[b * Sv + s + 1];   // causal shift
    }
    t[n] = tv;
}

// ---- fused GEMM + exp-reduce + gold gather --------------------------------
// 8-phase schedule with ONE-PHASE REGISTER PREFETCH: phase p issues the
// ds_reads for phase p+1's fragments, then waits only lgkmcnt(K_issued) so
// the PREVIOUS phase's reads are complete -> current reads drain under the
// MFMA cluster (LDS port || MFMA pipe overlap). Double frag sets aE/aO,
// bE/bO (all statically indexed).
// Stage map: ph1: A1.h1<-2j+1; ph2/3: B0<-2j+2; ph4/5: A0<-2j+2;
//            ph6/7: B1<-2j+3; ph8: A1.h0<-2j+3.
// Counted waits: vm8@ph1, vm4@ph3, vm6@ph7; >=4 loads always in flight.
// Peel: vm0@ph3, no reads at ph8.
// NOTE: natural blockIdx mapping (R0=bx, C0=by) is deliberate — round-3
// measurement showed an XCD remap TRIPLES HBM fetch: natural order pins a
// fixed 4MB hbf set per XCD in L2 and lets all XCDs share one hot B-panel.
// LDS XOR-swizzle (chunk ^= row&7) on the PRODUCER side (global src perm).
__global__ __launch_bounds__(512, 2)
void ce_gemm(const unsigned short* __restrict__ hbf,
             const unsigned short* __restrict__ wbf,
             const int* __restrict__ t,
             float* __restrict__ sumexp,
             float* __restrict__ gold) {
    __shared__ unsigned short lds_a[2][BM * BK];   // 2 x 32 KiB
    __shared__ unsigned short lds_b[2][BM * BK];   // 2 x 32 KiB
    __shared__ float lds_rowsum[BM];
    __shared__ int lds_t[BM];

    const int tid  = threadIdx.x;
    const int lane = tid & 63;
    const int wave = tid >> 6;      // 0..7
    const int wr   = wave >> 2;     // 0..1
    const int wc   = wave & 3;      // 0..3
    const int quad = lane >> 4;
    const int l15  = lane & 15;
    const int R0   = blockIdx.x * BM;
    const int C0   = blockIdx.y * BM;

    f32x4 acc[8][4];
    const f32x4 z = {0.f, 0.f, 0.f, 0.f};
#pragma unroll
    for (int mi = 0; mi < 8; ++mi)
#pragma unroll
        for (int ni = 0; ni < 4; ++ni)
            acc[mi][ni] = z;

    // staging: thread tid owns LDS chunk (row = tid>>3, jl = tid&7);
    // fetches global chunk jg = jl ^ (row & 7) -> swizzled LDS layout.
    const int ld_r = tid >> 3;                       // 0..63
    const int jg   = (tid & 7) ^ (ld_r & 7);
    const unsigned short* ga = hbf + (size_t)(R0 + ld_r) * Dv + jg * 8;
    const unsigned short* gb = wbf + (size_t)(C0 + ld_r) * Dv + jg * 8;

#define STAGE_HALF(DSTARR, GBASE, KT, H)                                    \
    do {                                                                    \
        _Pragma("unroll")                                                   \
        for (int _i = 2 * (H); _i < 2 * (H) + 2; ++_i) {                    \
            __builtin_amdgcn_global_load_lds(                               \
                (gptr_t)((GBASE) + (size_t)_i * 64 * Dv + (KT) * BK),       \
                (lptr_t)(&DSTARR[tid * 8 + _i * 4096]), 16, 0, 0);          \
        }                                                                   \
    } while (0)

#define LDSF(BASE, R, C) \
    (*(const bf16x8*)((BASE) + (R) * BK + (((C) ^ ((R) & 7)) * 8)))

#define VM8 asm volatile("s_waitcnt vmcnt(8)" ::: "memory")
#define VM6 asm volatile("s_waitcnt vmcnt(6)" ::: "memory")
#define VM4 asm volatile("s_waitcnt vmcnt(4)" ::: "memory")
#define VM0 asm volatile("s_waitcnt vmcnt(0)" ::: "memory")
#define NOVM ((void)0)
#define NOSTG ((void)0)

// Phase: MFMA quadrant QM from frag sets AU/BU (prefetched last phase);
// prefetch quadrant QR of lds_a[ARB] into AL (and, if LB, all-B of
// lds_b[BRB] into BL); stage STG; wait lgkmcnt(LGKM)=reads-just-issued so
// only the PREVIOUS phase's reads are forced complete.
#define PHASE(QM, AU, QR, ARB, AL, BU, LB, BRB, BL, LGKM, VMW, STG)         \
    do {                                                                    \
        STG;                                                                \
        if ((QR) >= 0) {                                                    \
            const unsigned short* ab_ = &lds_a[ARB][0];                     \
            const int r0_ = (QR) * 64 + wr * 16 + l15;                      \
            AL[0] = LDSF(ab_, r0_, quad);                                   \
            AL[1] = LDSF(ab_, r0_, quad + 4);                               \
            AL[2] = LDSF(ab_, r0_ + 32, quad);                              \
            AL[3] = LDSF(ab_, r0_ + 32, quad + 4);                          \
        }                                                                   \
        if (LB) {                                                           \
            const unsigned short* bb_ = &lds_b[BRB][0];                     \
            _Pragma("unroll")                                               \
            for (int ni_ = 0; ni_ < 4; ++ni_) {                             \
                const int br_ = wc * 64 + ni_ * 16 + l15;                   \
                BL[ni_][0] = LDSF(bb_, br_, quad);                          \
                BL[ni_][1] = LDSF(bb_, br_, quad + 4);                      \
            }                                                               \
        }                                                                   \
        __builtin_amdgcn_s_barrier();                                       \
        asm volatile("s_waitcnt lgkmcnt(" LGKM ")" ::: "memory");           \
        __builtin_amdgcn_sched_barrier(0);                                  \
        __builtin_amdgcn_s_setprio(1);                                      \
        _Pragma("unroll")                                                   \
        for (int ni_ = 0; ni_ < 4; ++ni_) {                                 \
            acc[2*(QM)][ni_] = __builtin_amdgcn_mfma_f32_16x16x32_bf16(     \
                AU[0], BU[ni_][0], acc[2*(QM)][ni_], 0, 0, 0);              \
            acc[2*(QM)][ni_] = __builtin_amdgcn_mfma_f32_16x16x32_bf16(     \
                AU[1], BU[ni_][1], acc[2*(QM)][ni_], 0, 0, 0);              \
        }                                                                   \
        _Pragma("unroll")                                                   \
        for (int ni_ = 0; ni_ < 4; ++ni_) {                                 \
            acc[2*(QM)+1][ni_] = __builtin_amdgcn_mfma_f32_16x16x32_bf16(   \
                AU[2], BU[ni_][0], acc[2*(QM)+1][ni_], 0, 0, 0);            \
            acc[2*(QM)+1][ni_] = __builtin_amdgcn_mfma_f32_16x16x32_bf16(   \
                AU[3], BU[ni_][1], acc[2*(QM)+1][ni_], 0, 0, 0);            \
        }                                                                   \
        __builtin_amdgcn_s_setprio(0);                                      \
        VMW;                                                                \
        __builtin_amdgcn_s_barrier();                                       \
    } while (0)

    bf16x8 aE[4], aO[4];
    bf16x8 bE[4][2], bO[4][2];

    // ---- prologue: stage t0 fully + t1 (B + A.h0); land t0; prefetch ----
    STAGE_HALF(lds_b[0], gb, 0, 0);
    STAGE_HALF(lds_b[0], gb, 0, 1);
    STAGE_HALF(lds_a[0], ga, 0, 0);
    STAGE_HALF(lds_a[0], ga, 0, 1);
    STAGE_HALF(lds_b[1], gb, 1, 0);
    STAGE_HALF(lds_b[1], gb, 1, 1);
    STAGE_HALF(lds_a[1], ga, 1, 0);
    asm volatile("s_waitcnt vmcnt(6)" ::: "memory");   // t0's 8 loads landed
    __builtin_amdgcn_s_barrier();

    // prologue prefetch for ph1: A0.Q0 -> aE, B0 -> bE (12 reads)
    {
        const unsigned short* ab_ = &lds_a[0][0];
        const int r0_ = 0 * 64 + wr * 16 + l15;
        aE[0] = LDSF(ab_, r0_, quad);
        aE[1] = LDSF(ab_, r0_, quad + 4);
        aE[2] = LDSF(ab_, r0_ + 32, quad);
        aE[3] = LDSF(ab_, r0_ + 32, quad + 4);
        const unsigned short* bb_ = &lds_b[0][0];
#pragma unroll
        for (int ni_ = 0; ni_ < 4; ++ni_) {
            const int br_ = wc * 64 + ni_ * 16 + l15;
            bE[ni_][0] = LDSF(bb_, br_, quad);
            bE[ni_][1] = LDSF(bb_, br_, quad + 4);
        }
    }

    // ---- main loop: iterations 0..14 (tiles 0..29) ----
#pragma unroll 1
    for (int j = 0; j < 15; ++j) {
        const int t1 = 2 * j + 1, t2 = 2 * j + 2, t3 = 2 * j + 3;
        PHASE(0, aE, 1, 0, aO, bE, 0, 0, bO, "4",  VM8,  STAGE_HALF(lds_a[1], ga, t1, 1));
        PHASE(1, aO, 2, 0, aE, bE, 0, 0, bO, "4",  NOVM, STAGE_HALF(lds_b[0], gb, t2, 0));
        PHASE(2, aE, 3, 0, aO, bE, 0, 0, bO, "4",  VM4,  STAGE_HALF(lds_b[0], gb, t2, 1));
        PHASE(3, aO, 0, 1, aE, bE, 1, 1, bO, "12", NOVM, STAGE_HALF(lds_a[0], ga, t2, 0));
        PHASE(0, aE, 1, 1, aO, bO, 0, 0, bE, "4",  NOVM, STAGE_HALF(lds_a[0], ga, t2, 1));
        PHASE(1, aO, 2, 1, aE, bO, 0, 0, bE, "4",  NOVM, STAGE_HALF(lds_b[1], gb, t3, 0));
        PHASE(2, aE, 3, 1, aO, bO, 0, 0, bE, "4",  VM6,  STAGE_HALF(lds_b[1], gb, t3, 1));
        PHASE(3, aO, 0, 0, aE, bO, 1, 0, bE, "12", NOVM, STAGE_HALF(lds_a[1], ga, t3, 0));
    }
    // ---- peeled last iteration (tiles 30, 31) ----
    PHASE(0, aE, 1, 0, aO, bE, 0, 0, bO, "4",  VM8,  STAGE_HALF(lds_a[1], ga, 31, 1));
    PHASE(1, aO, 2, 0, aE, bE, 0, 0, bO, "4",  NOVM, NOSTG);
    PHASE(2, aE, 3, 0, aO, bE, 0, 0, bO, "4",  VM0,  NOSTG);
    PHASE(3, aO, 0, 1, aE, bE, 1, 1, bO, "12", NOVM, NOSTG);
    PHASE(0, aE, 1, 1, aO, bO, 0, 0, bE, "4",  NOVM, NOSTG);
    PHASE(1, aO, 2, 1, aE, bO, 0, 0, bE, "4",  NOVM, NOSTG);
    PHASE(2, aE, 3, 1, aO, bO, 0, 0, bE, "4",  NOVM, NOSTG);
    PHASE(3, aO, -1, 0, aE, bO, 0, 0, bE, "0", NOVM, NOSTG);

#undef PHASE
#undef STAGE_HALF

    // ---- fused epilogue: exp + row-sum + gold capture ----
    __syncthreads();
    if (tid < BM) {
        lds_rowsum[tid] = 0.0f;
        lds_t[tid] = t[R0 + tid];
    }
    __syncthreads();

#pragma unroll
    for (int mi = 0; mi < 8; ++mi) {
#pragma unroll
        for (int reg = 0; reg < 4; ++reg) {
            // interleaved row map: wave wr's mi-th block = mi*32 + wr*16
            const int lrow = mi * 32 + wr * 16 + quad * 4 + reg;
            const int grow = R0 + lrow;
            const int lbl  = lds_t[lrow];
            float s = 0.0f;
#pragma unroll
            for (int ni = 0; ni < 4; ++ni) {
                const float v = acc[mi][ni][reg];
                s += __expf(v);
                const int gcol = C0 + wc * 64 + ni * 16 + l15;
                if (lbl == gcol) gold[grow] = v;                // unique writer
            }
#pragma unroll
            for (int off = 1; off < 16; off <<= 1)
                s += __shfl_xor(s, off, 64);
            if (l15 == 0) atomicAdd(&lds_rowsum[lrow], s);
        }
    }
    __syncthreads();
    if (tid < BM) {
        const int grow = R0 + tid;
        if (grow < Nv) atomicAdd(&sumexp[grow], lds_rowsum[tid]);
    }
}

// ---- final scalar: mean over valid rows of log(sumexp) - gold -------------
__global__ void ce_finalize(const float* __restrict__ sumexp,
                            const float* __restrict__ gold,
                            const int* __restrict__ t,
                            float* __restrict__ out) {
    __shared__ float ssum[4];
    __shared__ float scnt[4];
    float s = 0.0f, cnt = 0.0f;
    for (int n = threadIdx.x; n < Nv; n += 256) {
        if (t[n] != IGNORE_INDEX) {
            s += logf(sumexp[n]) - gold[n];
            cnt += 1.0f;
        }
    }
#pragma unroll
    for (int off = 32; off > 0; off >>= 1) {
        s += __shfl_down(s, off, 64);
        cnt += __shfl_down(cnt, off, 64);
    }
    const int wid = threadIdx.x >> 6;
    if ((threadIdx.x & 63) == 0) { ssum[wid] = s; scnt[wid] = cnt; }
    __syncthreads();
    if (threadIdx.x == 0) {
        float S = 0.0f, C = 0.0f;
        for (int i = 0; i < 4; ++i) { S += ssum[i]; C += scnt[i]; }
        out[0] = S / fmaxf(C, 1.0f);
    }
}

extern "C" void kernel_launch(void* const* d_in, const int* in_sizes, int n_in,
                              void* d_out, int out_size, void* d_ws, size_t ws_size,
                              hipStream_t stream) {
    const float* h      = (const float*)d_in[0];   // [4, 2048, 2048] fp32
    const float* w      = (const float*)d_in[1];   // [32000, 2048] fp32
    const int*   labels = (const int*)d_in[2];     // [4, 2048] int
    float* out = (float*)d_out;

    char* ws = (char*)d_ws;
    unsigned short* hbf = (unsigned short*)ws;                                   // 33.6 MB
    unsigned short* wbf = (unsigned short*)(ws + (size_t)NP * Dv * 2);           // 131 MB
    char* tail = ws + (size_t)NP * Dv * 2 + (size_t)Vv * Dv * 2;
    float* sumexp = (float*)tail;
    float* gold   = (float*)(tail + (size_t)NP * 4);
    int*   t      = (int*)(tail + (size_t)NP * 8);

    hipLaunchKernelGGL(convert_w_kernel, dim3((Vv * Dv / 4) / 256), dim3(256), 0, stream, w, wbf);
    hipLaunchKernelGGL(convert_h_kernel, dim3((NP * Dv / 4) / 256), dim3(256), 0, stream, h, hbf);
    hipLaunchKernelGGL(prep_meta_kernel, dim3(NP / 256), dim3(256), 0, stream, labels, t, sumexp, gold);
    hipLaunchKernelGGL(ce_gemm, dim3(NP / BM, Vv / BM), dim3(512), 0, stream,
                       hbf, wbf, t, sumexp, gold);
    hipLaunchKernelGGL(ce_finalize, dim3(1), dim3(256), 0, stream, sumexp, gold, t, out);
}

// Round 5
// 1445.490 us; speedup vs baseline: 1.0416x; 1.0017x over previous
//
#include <hip/hip_runtime.h>
#include <stdint.h>

#define IGNORE_INDEX (-100)

typedef __attribute__((ext_vector_type(8))) short bf16x8;
typedef __attribute__((ext_vector_type(4))) float f32x4;

static constexpr int Bv = 4, Sv = 2048, Dv = 2048, Vv = 32000;
static constexpr int Nv = Bv * (Sv - 1);   // 8188 valid rows
static constexpr int NP = 8192;            // padded row count
static constexpr int BM = 256;             // block tile (rows and cols)
static constexpr int BK = 64;              // K-step
static constexpr int NT = Dv / BK;         // 32 K-tiles (16 iterations x 2)

typedef const __attribute__((address_space(1))) unsigned int* gptr_t;
typedef __attribute__((address_space(3))) unsigned int* lptr_t;

__device__ __forceinline__ unsigned short f2bf(float f) {
    unsigned int u = __float_as_uint(f);
    u += 0x7fffu + ((u >> 16) & 1u);   // round-to-nearest-even
    return (unsigned short)(u >> 16);
}

// ---- fp32 -> bf16 for lm_head_weight [V, D] -------------------------------
__global__ void convert_w_kernel(const float* __restrict__ w,
                                 unsigned short* __restrict__ wbf) {
    int i = blockIdx.x * blockDim.x + threadIdx.x;   // one float4
    const float4 v = ((const float4*)w)[i];
    ushort4 o;
    o.x = f2bf(v.x); o.y = f2bf(v.y); o.z = f2bf(v.z); o.w = f2bf(v.w);
    ((ushort4*)wbf)[i] = o;
}

// ---- fp32 -> bf16 for shifted hidden states, rows padded to 8192 ----------
__global__ void convert_h_kernel(const float* __restrict__ h,
                                 unsigned short* __restrict__ hbf) {
    int i = blockIdx.x * blockDim.x + threadIdx.x;   // one float4
    int e0 = i * 4;
    int n = e0 >> 11;       // / 2048
    int d = e0 & 2047;
    ushort4 o;
    if (n < Nv) {
        int b = n / 2047;            // batch
        int s = n - b * 2047;        // position 0..2046
        const float4 v = *(const float4*)(h + ((size_t)b * Sv + s) * Dv + d);
        o.x = f2bf(v.x); o.y = f2bf(v.y); o.z = f2bf(v.z); o.w = f2bf(v.w);
    } else {
        o.x = 0; o.y = 0; o.z = 0; o.w = 0;
    }
    ((ushort4*)hbf)[i] = o;
}

// ---- shifted labels + zero-init of accumulators ---------------------------
__global__ void prep_meta_kernel(const int* __restrict__ labels,
                                 int* __restrict__ t,
                                 float* __restrict__ sumexp,
                                 float* __restrict__ gold) {
    int n = blockIdx.x * blockDim.x + threadIdx.x;
    if (n >= NP) return;
    sumexp[n] = 0.0f;
    gold[n] = 0.0f;
    int tv = IGNORE_INDEX;
    if (n < Nv) {
        int b = n / 2047;
        int s = n - b * 2047;
        tv = labels[b * Sv + s + 1];   // causal shift
    }
    t[n] = tv;
}

// ---- fused GEMM + exp-reduce + gold gather --------------------------------
// 8-phase schedule, COMPILER-SCHEDULED LDS WAITS: each phase issues its
// ds_reads before the barrier and the MFMA cluster consumes them with the
// compiler's fine-grained lgkmcnt(4/3/1/0) — the first MFMA starts as soon
// as its own operands land, and the remaining reads drain UNDER the MFMA
// cluster. (Round-2/4 measurement: an explicit lgkmcnt(0)/sched_barrier(0)
// before the MFMAs serializes the full LDS drain against the MFMA block —
// MfmaUtil capped at ~45%.)
// Stage map (iter j): ph1: A1.h1<-2j+1; ph2/3: B0<-2j+2; ph4/5: A0<-2j+2;
// ph6/7: B1<-2j+3; ph8: A1.h0<-2j+3. Counted vmcnt(6) at phases 4/8 only
// (steady state: 6 loads in flight after each wait); peel drains at ph4.
// NOTE: natural blockIdx mapping (R0=bx, C0=by) is deliberate — round-3
// measurement showed an XCD remap TRIPLES HBM fetch: natural order pins a
// fixed 4MB hbf set per XCD in L2 and lets all XCDs share one hot B-panel.
// LDS XOR-swizzle (chunk ^= row&7) on the PRODUCER side (global src perm).
__global__ __launch_bounds__(512, 2)
void ce_gemm(const unsigned short* __restrict__ hbf,
             const unsigned short* __restrict__ wbf,
             const int* __restrict__ t,
             float* __restrict__ sumexp,
             float* __restrict__ gold) {
    __shared__ unsigned short lds_a[2][BM * BK];   // 2 x 32 KiB
    __shared__ unsigned short lds_b[2][BM * BK];   // 2 x 32 KiB
    __shared__ float lds_rowsum[BM];
    __shared__ int lds_t[BM];

    const int tid  = threadIdx.x;
    const int lane = tid & 63;
    const int wave = tid >> 6;      // 0..7
    const int wr   = wave >> 2;     // 0..1
    const int wc   = wave & 3;      // 0..3
    const int quad = lane >> 4;
    const int l15  = lane & 15;
    const int R0   = blockIdx.x * BM;
    const int C0   = blockIdx.y * BM;

    f32x4 acc[8][4];
    const f32x4 z = {0.f, 0.f, 0.f, 0.f};
#pragma unroll
    for (int mi = 0; mi < 8; ++mi)
#pragma unroll
        for (int ni = 0; ni < 4; ++ni)
            acc[mi][ni] = z;

    // staging: thread tid owns LDS chunk (row = tid>>3, jl = tid&7);
    // fetches global chunk jg = jl ^ (row & 7) -> swizzled LDS layout.
    const int ld_r = tid >> 3;                       // 0..63
    const int jg   = (tid & 7) ^ (ld_r & 7);
    const unsigned short* ga = hbf + (size_t)(R0 + ld_r) * Dv + jg * 8;
    const unsigned short* gb = wbf + (size_t)(C0 + ld_r) * Dv + jg * 8;

#define STAGE_HALF(DSTARR, GBASE, KT, H)                                    \
    do {                                                                    \
        _Pragma("unroll")                                                   \
        for (int _i = 2 * (H); _i < 2 * (H) + 2; ++_i) {                    \
            __builtin_amdgcn_global_load_lds(                               \
                (gptr_t)((GBASE) + (size_t)_i * 64 * Dv + (KT) * BK),       \
                (lptr_t)(&DSTARR[tid * 8 + _i * 4096]), 16, 0, 0);          \
        }                                                                   \
    } while (0)

#define LDSF(BASE, R, C) \
    (*(const bf16x8*)((BASE) + (R) * BK + (((C) ^ ((R) & 7)) * 8)))

#define VM6 asm volatile("s_waitcnt vmcnt(6)" ::: "memory")
#define VM0 asm volatile("s_waitcnt vmcnt(0)" ::: "memory")
#define NOVM ((void)0)
#define NOSTG ((void)0)

// One phase: quadrant Q of the K-tile in lds buffer ABUF.
// LOADB!=0: also (re)load the 8 B-fragments from lds_b[BBUF] into bfr.
// Stage statement is __VA_ARGS__; VMW is the counted vmcnt wait (or NOVM).
// No explicit lgkmcnt / sched_barrier: the compiler inserts fine-grained
// lgkmcnt before each first-consuming MFMA, overlapping LDS drain w/ MFMA.
#define PHASE(ABUF, Q, LOADB, BBUF, VMW, ...)                               \
    do {                                                                    \
        bf16x8 a0_, a1_, a2_, a3_;                                          \
        __VA_ARGS__;                                                        \
        {                                                                   \
            const int r0_ = (2 * (Q)) * 32 + wr * 16 + l15;                 \
            const int r1_ = (2 * (Q) + 1) * 32 + wr * 16 + l15;             \
            const unsigned short* ab_ = &lds_a[ABUF][0];                    \
            a0_ = LDSF(ab_, r0_, quad);                                     \
            a1_ = LDSF(ab_, r0_, quad + 4);                                 \
            a2_ = LDSF(ab_, r1_, quad);                                     \
            a3_ = LDSF(ab_, r1_, quad + 4);                                 \
        }                                                                   \
        if (LOADB) {                                                        \
            const unsigned short* bb_ = &lds_b[BBUF][0];                    \
            _Pragma("unroll")                                               \
            for (int ni_ = 0; ni_ < 4; ++ni_) {                             \
                const int br_ = wc * 64 + ni_ * 16 + l15;                   \
                bfr[ni_][0] = LDSF(bb_, br_, quad);                         \
                bfr[ni_][1] = LDSF(bb_, br_, quad + 4);                     \
            }                                                               \
        }                                                                   \
        __builtin_amdgcn_s_barrier();                                       \
        __builtin_amdgcn_s_setprio(1);                                      \
        {                                                                   \
            const int miA_ = 2 * (Q), miB_ = 2 * (Q) + 1;                   \
            _Pragma("unroll")                                               \
            for (int ni_ = 0; ni_ < 4; ++ni_) {                             \
                acc[miA_][ni_] = __builtin_amdgcn_mfma_f32_16x16x32_bf16(   \
                    a0_, bfr[ni_][0], acc[miA_][ni_], 0, 0, 0);             \
                acc[miA_][ni_] = __builtin_amdgcn_mfma_f32_16x16x32_bf16(   \
                    a1_, bfr[ni_][1], acc[miA_][ni_], 0, 0, 0);             \
            }                                                               \
            _Pragma("unroll")                                               \
            for (int ni_ = 0; ni_ < 4; ++ni_) {                             \
                acc[miB_][ni_] = __builtin_amdgcn_mfma_f32_16x16x32_bf16(   \
                    a2_, bfr[ni_][0], acc[miB_][ni_], 0, 0, 0);             \
                acc[miB_][ni_] = __builtin_amdgcn_mfma_f32_16x16x32_bf16(   \
                    a3_, bfr[ni_][1], acc[miB_][ni_], 0, 0, 0);             \
            }                                                               \
        }                                                                   \
        __builtin_amdgcn_s_setprio(0);                                      \
        VMW;                                                                \
        __builtin_amdgcn_s_barrier();                                       \
    } while (0)

    bf16x8 bfr[4][2];

    // ---- prologue: tile0 complete (8 loads) + tile1 partial (6 loads) ----
    STAGE_HALF(lds_b[0], gb, 0, 0);
    STAGE_HALF(lds_b[0], gb, 0, 1);
    STAGE_HALF(lds_a[0], ga, 0, 0);
    STAGE_HALF(lds_a[0], ga, 0, 1);
    STAGE_HALF(lds_b[1], gb, 1, 0);
    STAGE_HALF(lds_b[1], gb, 1, 1);
    STAGE_HALF(lds_a[1], ga, 1, 0);
    asm volatile("s_waitcnt vmcnt(6)" ::: "memory");   // t0's 8 loads landed
    __builtin_amdgcn_s_barrier();

    // ---- main loop: iterations 0..14 (tiles 0..29), full stage map ----
#pragma unroll 1
    for (int j = 0; j < 15; ++j) {
        const int t1 = 2 * j + 1, t2 = 2 * j + 2, t3 = 2 * j + 3;
        PHASE(0, 0, 1, 0, NOVM, STAGE_HALF(lds_a[1], ga, t1, 1));
        PHASE(0, 1, 0, 0, NOVM, STAGE_HALF(lds_b[0], gb, t2, 0));
        PHASE(0, 2, 0, 0, NOVM, STAGE_HALF(lds_b[0], gb, t2, 1));
        PHASE(0, 3, 0, 0, VM6,  STAGE_HALF(lds_a[0], ga, t2, 0));
        PHASE(1, 0, 1, 1, NOVM, STAGE_HALF(lds_a[0], ga, t2, 1));
        PHASE(1, 1, 0, 1, NOVM, STAGE_HALF(lds_b[1], gb, t3, 0));
        PHASE(1, 2, 0, 1, NOVM, STAGE_HALF(lds_b[1], gb, t3, 1));
        PHASE(1, 3, 0, 1, VM6,  STAGE_HALF(lds_a[1], ga, t3, 0));
    }
    // ---- peeled last iteration (tiles 30, 31): only ph1 stages ----
    PHASE(0, 0, 1, 0, NOVM, STAGE_HALF(lds_a[1], ga, 31, 1));
    PHASE(0, 1, 0, 0, NOVM, NOSTG);
    PHASE(0, 2, 0, 0, NOVM, NOSTG);
    PHASE(0, 3, 0, 0, VM0,  NOSTG);        // drain: tile31 A.h1 must land
    PHASE(1, 0, 1, 1, NOVM, NOSTG);
    PHASE(1, 1, 0, 1, NOVM, NOSTG);
    PHASE(1, 2, 0, 1, NOVM, NOSTG);
    PHASE(1, 3, 0, 1, NOVM, NOSTG);

#undef PHASE
#undef STAGE_HALF

    // ---- fused epilogue: exp + row-sum + gold capture ----
    __syncthreads();
    if (tid < BM) {
        lds_rowsum[tid] = 0.0f;
        lds_t[tid] = t[R0 + tid];
    }
    __syncthreads();

#pragma unroll
    for (int mi = 0; mi < 8; ++mi) {
#pragma unroll
        for (int reg = 0; reg < 4; ++reg) {
            // interleaved row map: wave wr's mi-th block = mi*32 + wr*16
            const int lrow = mi * 32 + wr * 16 + quad * 4 + reg;
            const int grow = R0 + lrow;
            const int lbl  = lds_t[lrow];
            float s = 0.0f;
#pragma unroll
            for (int ni = 0; ni < 4; ++ni) {
                const float v = acc[mi][ni][reg];
                s += __expf(v);
                const int gcol = C0 + wc * 64 + ni * 16 + l15;
                if (lbl == gcol) gold[grow] = v;                // unique writer
            }
#pragma unroll
            for (int off = 1; off < 16; off <<= 1)
                s += __shfl_xor(s, off, 64);
            if (l15 == 0) atomicAdd(&lds_rowsum[lrow], s);
        }
    }
    __syncthreads();
    if (tid < BM) {
        const int grow = R0 + tid;
        if (grow < Nv) atomicAdd(&sumexp[grow], lds_rowsum[tid]);
    }
}

// ---- final scalar: mean over valid rows of log(sumexp) - gold -------------
__global__ void ce_finalize(const float* __restrict__ sumexp,
                            const float* __restrict__ gold,
                            const int* __restrict__ t,
                            float* __restrict__ out) {
    __shared__ float ssum[4];
    __shared__ float scnt[4];
    float s = 0.0f, cnt = 0.0f;
    for (int n = threadIdx.x; n < Nv; n += 256) {
        if (t[n] != IGNORE_INDEX) {
            s += logf(sumexp[n]) - gold[n];
            cnt += 1.0f;
        }
    }
#pragma unroll
    for (int off = 32; off > 0; off >>= 1) {
        s += __shfl_down(s, off, 64);
        cnt += __shfl_down(cnt, off, 64);
    }
    const int wid = threadIdx.x >> 6;
    if ((threadIdx.x & 63) == 0) { ssum[wid] = s; scnt[wid] = cnt; }
    __syncthreads();
    if (threadIdx.x == 0) {
        float S = 0.0f, C = 0.0f;
        for (int i = 0; i < 4; ++i) { S += ssum[i]; C += scnt[i]; }
        out[0] = S / fmaxf(C, 1.0f);
    }
}

extern "C" void kernel_launch(void* const* d_in, const int* in_sizes, int n_in,
                              void* d_out, int out_size, void* d_ws, size_t ws_size,
                              hipStream_t stream) {
    const float* h      = (const float*)d_in[0];   // [4, 2048, 2048] fp32
    const float* w      = (const float*)d_in[1];   // [32000, 2048] fp32
    const int*   labels = (const int*)d_in[2];     // [4, 2048] int
    float* out = (float*)d_out;

    char* ws = (char*)d_ws;
    unsigned short* hbf = (unsigned short*)ws;                                   // 33.6 MB
    unsigned short* wbf = (unsigned short*)(ws + (size_t)NP * Dv * 2);           // 131 MB
    char* tail = ws + (size_t)NP * Dv * 2 + (size_t)Vv * Dv * 2;
    float* sumexp = (float*)tail;
    float* gold   = (float*)(tail + (size_t)NP * 4);
    int*   t      = (int*)(tail + (size_t)NP * 8);

    hipLaunchKernelGGL(convert_w_kernel, dim3((Vv * Dv / 4) / 256), dim3(256), 0, stream, w, wbf);
    hipLaunchKernelGGL(convert_h_kernel, dim3((NP * Dv / 4) / 256), dim3(256), 0, stream, h, hbf);
    hipLaunchKernelGGL(prep_meta_kernel, dim3(NP / 256), dim3(256), 0, stream, labels, t, sumexp, gold);
    hipLaunchKernelGGL(ce_gemm, dim3(NP / BM, Vv / BM), dim3(512), 0, stream,
                       hbf, wbf, t, sumexp, gold);
    hipLaunchKernelGGL(ce_finalize, dim3(1), dim3(256), 0, stream, sumexp, gold, t, out);
}

// Round 6
// 1350.956 us; speedup vs baseline: 1.1144x; 1.0700x over previous
//
#include <hip/hip_runtime.h>
#include <stdint.h>

#define IGNORE_INDEX (-100)

typedef __attribute__((ext_vector_type(8))) short bf16x8;
typedef __attribute__((ext_vector_type(4))) float f32x4;

static constexpr int Bv = 4, Sv = 2048, Dv = 2048, Vv = 32000;
static constexpr int Nv = Bv * (Sv - 1);   // 8188 valid rows
static constexpr int NP = 8192;            // padded row count
static constexpr int TM = 128;             // block tile rows
static constexpr int TN = 256;             // block tile cols
static constexpr int BK = 64;              // K-step

typedef const __attribute__((address_space(1))) unsigned int* gptr_t;
typedef __attribute__((address_space(3))) unsigned int* lptr_t;

__device__ __forceinline__ unsigned short f2bf(float f) {
    unsigned int u = __float_as_uint(f);
    u += 0x7fffu + ((u >> 16) & 1u);   // round-to-nearest-even
    return (unsigned short)(u >> 16);
}

// ---- fp32 -> bf16 for lm_head_weight [V, D] -------------------------------
__global__ void convert_w_kernel(const float* __restrict__ w,
                                 unsigned short* __restrict__ wbf) {
    int i = blockIdx.x * blockDim.x + threadIdx.x;   // one float4
    const float4 v = ((const float4*)w)[i];
    ushort4 o;
    o.x = f2bf(v.x); o.y = f2bf(v.y); o.z = f2bf(v.z); o.w = f2bf(v.w);
    ((ushort4*)wbf)[i] = o;
}

// ---- fp32 -> bf16 for shifted hidden states, rows padded to 8192 ----------
__global__ void convert_h_kernel(const float* __restrict__ h,
                                 unsigned short* __restrict__ hbf) {
    int i = blockIdx.x * blockDim.x + threadIdx.x;   // one float4
    int e0 = i * 4;
    int n = e0 >> 11;       // / 2048
    int d = e0 & 2047;
    ushort4 o;
    if (n < Nv) {
        int b = n / 2047;            // batch
        int s = n - b * 2047;        // position 0..2046
        const float4 v = *(const float4*)(h + ((size_t)b * Sv + s) * Dv + d);
        o.x = f2bf(v.x); o.y = f2bf(v.y); o.z = f2bf(v.z); o.w = f2bf(v.w);
    } else {
        o.x = 0; o.y = 0; o.z = 0; o.w = 0;
    }
    ((ushort4*)hbf)[i] = o;
}

// ---- shifted labels + zero-init of accumulators ---------------------------
__global__ void prep_meta_kernel(const int* __restrict__ labels,
                                 int* __restrict__ t,
                                 float* __restrict__ sumexp,
                                 float* __restrict__ gold) {
    int n = blockIdx.x * blockDim.x + threadIdx.x;
    if (n >= NP) return;
    sumexp[n] = 0.0f;
    gold[n] = 0.0f;
    int tv = IGNORE_INDEX;
    if (n < Nv) {
        int b = n / 2047;
        int s = n - b * 2047;
        tv = labels[b * Sv + s + 1];   // causal shift
    }
    t[n] = tv;
}

// ---- fused GEMM + exp-reduce + gold gather --------------------------------
// 128x256 tile, 4 waves (2x2 grid, 64x128 per wave), BK=64, single-buffered
// LDS (A 16K + B 32K = 48K) with the ROUND-0 drain structure: 2 barriers per
// K-tile, compiler-inserted vmcnt(0) drain at the post-stage barrier, and
// 2 resident blocks/CU providing inter-block stagger (the mechanism that
// made round-0's 128^2 run at ~86% of its LDS-port bound).
// Rationale: round-0 is LDS-PORT-bound (1018 cyc/K-tile port vs 621 MFMA).
// The 2x2/64x128 wave grid halves per-output LDS reads (port 1527 cyc per
// K-tile for 2x the output area). 256^2 8-wave lockstep variants (rounds
// 1-5) all failed: 1 block/CU + per-phase barriers serialize port & MFMA.
// NOTE: natural blockIdx mapping (rows=bx) is deliberate — round-3 showed
// an XCD remap TRIPLES HBM fetch (destroys per-XCD L2 residency of hbf and
// cross-XCD sharing of the hot B-panel).
// LDS XOR-swizzle (chunk ^= row&7) on the PRODUCER side (global src perm).
__global__ __launch_bounds__(256, 2)
void ce_gemm(const unsigned short* __restrict__ hbf,
             const unsigned short* __restrict__ wbf,
             const int* __restrict__ t,
             float* __restrict__ sumexp,
             float* __restrict__ gold) {
    __shared__ unsigned short lds_a[TM * BK];   // 16 KiB
    __shared__ unsigned short lds_b[TN * BK];   // 32 KiB
    __shared__ float lds_rowsum[TM];
    __shared__ int lds_t[TM];

    const int tid  = threadIdx.x;
    const int lane = tid & 63;
    const int wave = tid >> 6;      // 0..3
    const int r    = wave >> 1;     // row half (64 rows each)
    const int c    = wave & 1;      // col half (128 cols each)
    const int quad = lane >> 4;
    const int l15  = lane & 15;
    const int R0   = blockIdx.x * TM;
    const int C0   = blockIdx.y * TN;

    f32x4 acc[4][8];
    const f32x4 z = {0.f, 0.f, 0.f, 0.f};
#pragma unroll
    for (int mi = 0; mi < 4; ++mi)
#pragma unroll
        for (int ni = 0; ni < 8; ++ni)
            acc[mi][ni] = z;

    // staging: thread tid owns LDS slot (row = tid>>3, chunk jl = tid&7);
    // it fetches global chunk jg = jl ^ (row & 7) -> swizzled LDS layout.
    // Row advances by 32 per iteration: (row&7) unchanged, swizzle valid.
    const int ld_r = tid >> 3;                       // 0..31
    const int jg   = (tid & 7) ^ (ld_r & 7);
    const unsigned short* ga = hbf + (size_t)(R0 + ld_r) * Dv + jg * 8;
    const unsigned short* gb = wbf + (size_t)(C0 + ld_r) * Dv + jg * 8;
    unsigned short* la = lds_a + tid * 8;
    unsigned short* lb = lds_b + tid * 8;

    for (int k0 = 0; k0 < Dv; k0 += BK) {
        __syncthreads();   // previous tile fully consumed
#pragma unroll
        for (int i = 0; i < 4; ++i) {       // A: rows 0..127
            __builtin_amdgcn_global_load_lds(
                (gptr_t)(ga + (size_t)i * 32 * Dv + k0),
                (lptr_t)(la + i * 2048), 16, 0, 0);
        }
#pragma unroll
        for (int i = 0; i < 8; ++i) {       // B: rows 0..255
            __builtin_amdgcn_global_load_lds(
                (gptr_t)(gb + (size_t)i * 32 * Dv + k0),
                (lptr_t)(lb + i * 2048), 16, 0, 0);
        }
        __syncthreads();   // drains vmcnt before LDS reads
#pragma unroll
        for (int ks = 0; ks < 2; ++ks) {
            const int cbase = quad + ks * 4;        // logical 16B-chunk index
            bf16x8 af[4], bfr[8];
#pragma unroll
            for (int mi = 0; mi < 4; ++mi) {
                const int arow = r * 64 + mi * 16 + l15;
                af[mi] = *(const bf16x8*)(lds_a + arow * BK + ((cbase ^ (arow & 7)) * 8));
            }
#pragma unroll
            for (int ni = 0; ni < 8; ++ni) {
                const int brow = c * 128 + ni * 16 + l15;
                bfr[ni] = *(const bf16x8*)(lds_b + brow * BK + ((cbase ^ (brow & 7)) * 8));
            }
#pragma unroll
            for (int mi = 0; mi < 4; ++mi)
#pragma unroll
                for (int ni = 0; ni < 8; ++ni)
                    acc[mi][ni] = __builtin_amdgcn_mfma_f32_16x16x32_bf16(
                        af[mi], bfr[ni], acc[mi][ni], 0, 0, 0);
        }
    }

    // ---- fused epilogue: exp + row-sum + gold capture ----
    __syncthreads();
    if (tid < TM) {
        lds_rowsum[tid] = 0.0f;
        lds_t[tid] = t[R0 + tid];
    }
    __syncthreads();

#pragma unroll
    for (int mi = 0; mi < 4; ++mi) {
#pragma unroll
        for (int reg = 0; reg < 4; ++reg) {
            const int lrow = r * 64 + mi * 16 + quad * 4 + reg;  // C/D row
            const int grow = R0 + lrow;
            const int lbl  = lds_t[lrow];
            float s = 0.0f;
#pragma unroll
            for (int ni = 0; ni < 8; ++ni) {
                const float v = acc[mi][ni][reg];
                s += __expf(v);
                const int gcol = C0 + c * 128 + ni * 16 + l15;   // C/D col
                if (lbl == gcol) gold[grow] = v;                  // unique writer
            }
            // reduce across the 16 column-lanes sharing this row
#pragma unroll
            for (int off = 1; off < 16; off <<= 1)
                s += __shfl_xor(s, off, 64);
            if (l15 == 0) atomicAdd(&lds_rowsum[lrow], s);
        }
    }
    __syncthreads();
    if (tid < TM) {
        const int grow = R0 + tid;
        if (grow < Nv) atomicAdd(&sumexp[grow], lds_rowsum[tid]);
    }
}

// ---- final scalar: mean over valid rows of log(sumexp) - gold -------------
__global__ void ce_finalize(const float* __restrict__ sumexp,
                            const float* __restrict__ gold,
                            const int* __restrict__ t,
                            float* __restrict__ out) {
    __shared__ float ssum[4];
    __shared__ float scnt[4];
    float s = 0.0f, cnt = 0.0f;
    for (int n = threadIdx.x; n < Nv; n += 256) {
        if (t[n] != IGNORE_INDEX) {
            s += logf(sumexp[n]) - gold[n];
            cnt += 1.0f;
        }
    }
#pragma unroll
    for (int off = 32; off > 0; off >>= 1) {
        s += __shfl_down(s, off, 64);
        cnt += __shfl_down(cnt, off, 64);
    }
    const int wid = threadIdx.x >> 6;
    if ((threadIdx.x & 63) == 0) { ssum[wid] = s; scnt[wid] = cnt; }
    __syncthreads();
    if (threadIdx.x == 0) {
        float S = 0.0f, C = 0.0f;
        for (int i = 0; i < 4; ++i) { S += ssum[i]; C += scnt[i]; }
        out[0] = S / fmaxf(C, 1.0f);
    }
}

extern "C" void kernel_launch(void* const* d_in, const int* in_sizes, int n_in,
                              void* d_out, int out_size, void* d_ws, size_t ws_size,
                              hipStream_t stream) {
    const float* h      = (const float*)d_in[0];   // [4, 2048, 2048] fp32
    const float* w      = (const float*)d_in[1];   // [32000, 2048] fp32
    const int*   labels = (const int*)d_in[2];     // [4, 2048] int
    float* out = (float*)d_out;

    char* ws = (char*)d_ws;
    unsigned short* hbf = (unsigned short*)ws;                                   // 33.6 MB
    unsigned short* wbf = (unsigned short*)(ws + (size_t)NP * Dv * 2);           // 131 MB
    char* tail = ws + (size_t)NP * Dv * 2 + (size_t)Vv * Dv * 2;
    float* sumexp = (float*)tail;
    float* gold   = (float*)(tail + (size_t)NP * 4);
    int*   t      = (int*)(tail + (size_t)NP * 8);

    hipLaunchKernelGGL(convert_w_kernel, dim3((Vv * Dv / 4) / 256), dim3(256), 0, stream, w, wbf);
    hipLaunchKernelGGL(convert_h_kernel, dim3((NP * Dv / 4) / 256), dim3(256), 0, stream, h, hbf);
    hipLaunchKernelGGL(prep_meta_kernel, dim3(NP / 256), dim3(256), 0, stream, labels, t, sumexp, gold);
    hipLaunchKernelGGL(ce_gemm, dim3(NP / TM, Vv / TN), dim3(256), 0, stream,
                       hbf, wbf, t, sumexp, gold);
    hipLaunchKernelGGL(ce_finalize, dim3(1), dim3(256), 0, stream, sumexp, gold, t, out);
}